// Round 7
// baseline (322.510 us; speedup 1.0000x reference)
//
#include <hip/hip_runtime.h>
#include <math.h>

#define D_MODEL 2048
#define KB_ 64
#define NCHUNK 32

typedef __bf16 bf16;
typedef __attribute__((ext_vector_type(8))) __bf16 bf16x8;
typedef __attribute__((ext_vector_type(2))) __bf16 bf16x2;
typedef __attribute__((ext_vector_type(4))) float f32x4;

// ---- workspace layout (float offsets) ----
#define OFF_COEFFS 0                            // [32][64][2048]
#define OFF_NSQ    (32 * 64 * 2048)             // [32][64][64] per-dtile sumsq partials
#define OFF_NORMS  (OFF_NSQ + 32 * 64 * 64)     // [32][64]
#define OFF_PARTR  (OFF_NORMS + 2048)           // [32][2048]
#define OFF_PARTI  (OFF_PARTR + 32 * 2048)      // [32][2048]
#define OFF_CTX    (OFF_PARTI + 32 * 2048)      // [2048]
#define OFF_CHEB2  (OFF_CTX + 2048)             // 32768 bf16 = 16384 floats

// ---------------------------------------------------------------------------
// K0: cheb2 = bf16(cheby), same [64][512] layout
// ---------------------------------------------------------------------------
__global__ __launch_bounds__(256) void k0_prep(
    const float* __restrict__ cheby, bf16* __restrict__ cheb2)
{
  int flat = blockIdx.x * 256 + threadIdx.x;   // 0..32767
  cheb2[flat] = (bf16)cheby[flat];
}

// ---------------------------------------------------------------------------
// K1: c-pair form. Block (dt, p) computes windows c=2p and c=2p+1 for a 32-d
// tile, reading 3 chunks (2p-1, 2p, 2p+1) instead of 4 — kills the 2x
// window-overlap re-read (268 -> 201 MB logical).
// 12 slices of 64 n; slice sl: chunk 2p-1+(sl>>2); window A (c=2p) active for
// sl<8 at cheby col sl*64; window B (c=2p+1) active for sl>=4 at col (sl-4)*64.
// 4 waves; wave w: bands [w*16,(w+1)*16) x 32 d x 2 windows.
// Epilogue: scale, store coeffs, per-band sumsq partials -> nsq_part[c][k][dt].
// ---------------------------------------------------------------------------
__global__ __launch_bounds__(256) void k1_mfma(
    const float* __restrict__ scan, const float* __restrict__ buf,
    const bf16* __restrict__ cheb2, float* __restrict__ coeffs,
    float* __restrict__ nsq_part)
{
  __shared__ bf16 Bs[32 * 72];   // [d][72]: 64 n-slots + pad

  const int t = threadIdx.x;
  const int dt = blockIdx.x;     // 0..63 d-tile (32 wide)
  const int p  = blockIdx.y;     // 0..15 window pair
  const int w = t >> 6, lane = t & 63;
  const int quad = lane >> 4, r16 = lane & 15;
  const int d0 = dt * 32;
  const int n0 = (t >> 3) * 2;   // staging: 2 n-rows per thread (0..62)
  const int d4 = (t & 7) * 4;    // staging: 4 d-cols per thread (0..28)
  const float* scan1 = scan + 8192 * 2048;

  f32x4 acc[2][2];               // [window][tn]
#pragma unroll
  for (int a = 0; a < 2; ++a)
#pragma unroll
    for (int b = 0; b < 2; ++b) acc[a][b] = (f32x4){0.f, 0.f, 0.f, 0.f};

  for (int sl = 0; sl < 12; ++sl) {
    const int q = sl & 3;
    // stage: rows n0..n0+1, cols d4..d4+3 of this 64n x 32d slice
    float vv[2][4];
    if (p == 0 && sl < 4) {
      const float* bp = buf + (256 + sl * 64 + n0) * 2048 + d0 + d4;
#pragma unroll
      for (int i = 0; i < 2; ++i) {
        float4 x = *(const float4*)(bp + i * 2048);
        vv[i][0] = x.x; vv[i][1] = x.y; vv[i][2] = x.z; vv[i][3] = x.w;
      }
    } else {
      const int jc = 2 * p - 1 + (sl >> 2);
      const int gbase = (jc * 256 + q * 64 + n0) * 2048 + d0 + d4;
#pragma unroll
      for (int i = 0; i < 2; ++i) {
        float4 a = *(const float4*)(scan + gbase + i * 2048);
        float4 b = *(const float4*)(scan1 + gbase + i * 2048);
        vv[i][0] = 0.5f * (a.x + b.x); vv[i][1] = 0.5f * (a.y + b.y);
        vv[i][2] = 0.5f * (a.z + b.z); vv[i][3] = 0.5f * (a.w + b.w);
      }
    }
    __syncthreads();   // prior slice's fragment reads done before overwrite
#pragma unroll
    for (int x = 0; x < 4; ++x) {
      bf16x2 e = {(bf16)vv[0][x], (bf16)vv[1][x]};
      *(bf16x2*)(Bs + (d4 + x) * 72 + n0) = e;
    }
    __syncthreads();

    const bool wa = (sl < 8), wb = (sl >= 4);
    const int colA = sl * 64, colB = (sl - 4) * 64;
    const int arow = (w * 16 + r16) * 512;
#pragma unroll
    for (int ks = 0; ks < 2; ++ks) {
      bf16x8 bfr[2];
#pragma unroll
      for (int tn = 0; tn < 2; ++tn)
        bfr[tn] = *(const bf16x8*)(Bs + (tn * 16 + r16) * 72 + ks * 32 + quad * 8);
      if (wa) {
        bf16x8 a = *(const bf16x8*)(cheb2 + arow + colA + ks * 32 + quad * 8);
#pragma unroll
        for (int tn = 0; tn < 2; ++tn)
          acc[0][tn] = __builtin_amdgcn_mfma_f32_16x16x32_bf16(a, bfr[tn], acc[0][tn], 0, 0, 0);
      }
      if (wb) {
        bf16x8 a = *(const bf16x8*)(cheb2 + arow + colB + ks * 32 + quad * 8);
#pragma unroll
        for (int tn = 0; tn < 2; ++tn)
          acc[1][tn] = __builtin_amdgcn_mfma_f32_16x16x32_bf16(a, bfr[tn], acc[1][tn], 0, 0, 0);
      }
    }
  }

  // epilogue: scale, store, per-band sumsq partials for both windows
  const float scale = 2.0f / 512.0f;
#pragma unroll
  for (int win = 0; win < 2; ++win) {
    const int c = 2 * p + win;
    float sq[4] = {0.f, 0.f, 0.f, 0.f};
#pragma unroll
    for (int tn = 0; tn < 2; ++tn) {
#pragma unroll
      for (int rr = 0; rr < 4; ++rr) {
        int band = w * 16 + quad * 4 + rr;
        float sc = (band == 0) ? scale * 0.5f : scale;
        float v = acc[win][tn][rr] * sc;
        coeffs[(c * 64 + band) * 2048 + d0 + tn * 16 + r16] = v;
        sq[rr] += v * v;
      }
    }
#pragma unroll
    for (int off = 8; off > 0; off >>= 1) {
#pragma unroll
      for (int rr = 0; rr < 4; ++rr) sq[rr] += __shfl_down(sq[rr], off);
    }
    if (r16 == 0) {
#pragma unroll
      for (int rr = 0; rr < 4; ++rr)
        nsq_part[(c * 64 + w * 16 + quad * 4 + rr) * 64 + dt] = sq[rr];
    }
  }
}

// ---------------------------------------------------------------------------
// K3: grid (3, 32).
//  x<2: finalize norms (from nsq_part) + partial binds per (c, d-half)
//  x==2: delta for k = c and c+32 -> dout[2048+k]
// ---------------------------------------------------------------------------
__global__ __launch_bounds__(256) void k3_bind(
    const float* __restrict__ coeffs, const float* __restrict__ nsq_part,
    const float* __restrict__ rr, const float* __restrict__ ri,
    float* __restrict__ part_r, float* __restrict__ part_i,
    float* __restrict__ norms, float* __restrict__ dout)
{
  const int tid = threadIdx.x;
  const int c = blockIdx.y;

  if (blockIdx.x == 2) {
    __shared__ float red[4];
#pragma unroll
    for (int kk = 0; kk < 2; ++kk) {
      int k = c + kk * 32;
      const float* p1 = coeffs + (31 * 64 + k) * 2048;
      const float* p0 = coeffs + (30 * 64 + k) * 2048;
      float s = 0.f;
#pragma unroll
      for (int i = 0; i < 2; ++i) {
        float4 a = *(const float4*)(p1 + tid * 4 + i * 1024);
        float4 b = *(const float4*)(p0 + tid * 4 + i * 1024);
        float x = a.x - b.x, y = a.y - b.y, z = a.z - b.z, ww = a.w - b.w;
        s += x * x + y * y + z * z + ww * ww;
      }
      for (int o = 32; o > 0; o >>= 1) s += __shfl_down(s, o, 64);
      if ((tid & 63) == 0) red[tid >> 6] = s;
      __syncthreads();
      if (tid == 0) dout[D_MODEL + k] = sqrtf(red[0] + red[1] + red[2] + red[3]);
      __syncthreads();
    }
    return;
  }

  __shared__ float inv_s[64];
  if (tid < 64) {
    float s = 0.f;
#pragma unroll
    for (int dtl = 0; dtl < 64; ++dtl) s += nsq_part[(c * 64 + tid) * 64 + dtl];
    float nrm = fmaxf(sqrtf(s), 1e-12f);
    inv_s[tid] = 1.0f / nrm;
    if (blockIdx.x == 0) norms[c * 64 + tid] = nrm;
  }
  __syncthreads();
  const int d4 = (blockIdx.x * 256 + tid) * 4;
  const float wc = 0.1f * powf(0.9f, (float)(31 - c));
  float4 ar = make_float4(0.f, 0.f, 0.f, 0.f);
  float4 ai = make_float4(0.f, 0.f, 0.f, 0.f);
  for (int k = 0; k < KB_; ++k) {
    float4 cf = *(const float4*)(coeffs + (c * 64 + k) * 2048 + d4);
    float inv = inv_s[k];
    float4 r = *(const float4*)(rr + k * D_MODEL + d4);
    float4 im = *(const float4*)(ri + k * D_MODEL + d4);
    float cx = cf.x * inv, cy = cf.y * inv, cz = cf.z * inv, cw = cf.w * inv;
    ar.x += cx * r.x; ar.y += cy * r.y; ar.z += cz * r.z; ar.w += cw * r.w;
    ai.x += cx * im.x; ai.y += cy * im.y; ai.z += cz * im.z; ai.w += cw * im.w;
  }
  *(float4*)(part_r + c * D_MODEL + d4) =
      make_float4(wc * ar.x, wc * ar.y, wc * ar.z, wc * ar.w);
  *(float4*)(part_i + c * D_MODEL + d4) =
      make_float4(wc * ai.x, wc * ai.y, wc * ai.z, wc * ai.w);
}

// ---------------------------------------------------------------------------
// K4: cnorms EMA + top-8 (redundant per block, cheap), vr/vi -> d_out, ctx
// ---------------------------------------------------------------------------
__global__ __launch_bounds__(256) void k4_ctx(
    const float* __restrict__ norms, const float* __restrict__ part_r,
    const float* __restrict__ part_i, const float* __restrict__ rr,
    const float* __restrict__ ri, const float* __restrict__ wbands,
    float* __restrict__ dout, float* __restrict__ ctx)
{
  __shared__ float cn_s[64];
  __shared__ int top_s[8];
  __shared__ float wgt_s[8];
  const int tid = threadIdx.x;
  const int d = blockIdx.x * 256 + tid;
  if (tid < 64) {
    float s = 0.f;
    for (int c = 0; c < NCHUNK; ++c) s = 0.9f * s + 0.1f * norms[c * 64 + tid];
    cn_s[tid] = fmaxf(s, 1e-12f);
  }
  __syncthreads();
  if (tid == 0) {
    unsigned long long taken = 0ULL;
    for (int jj = 0; jj < 8; ++jj) {
      float best = -1.f;
      int bi = 0;
      for (int k = 0; k < 64; ++k) {
        float dv = dout[D_MODEL + k];
        if (!((taken >> k) & 1ULL) && dv > best) { best = dv; bi = k; }
      }
      taken |= (1ULL << bi);
      top_s[jj] = bi;
      wgt_s[jj] = log1pf(expf(wbands[bi]));  // softplus
    }
  }
  __syncthreads();
  float sr = 0.f, si = 0.f;
  for (int c = 0; c < NCHUNK; ++c) {
    sr += part_r[c * D_MODEL + d];
    si += part_i[c * D_MODEL + d];
  }
  dout[D_MODEL + KB_ + d] = sr;
  dout[D_MODEL + KB_ + D_MODEL + d] = si;
  float cx = 0.f;
#pragma unroll
  for (int jj = 0; jj < 8; ++jj) {
    int k = top_s[jj];
    cx += wgt_s[jj] * (sr * rr[k * D_MODEL + d] + si * ri[k * D_MODEL + d]) * cn_s[k];
  }
  ctx[d] = cx;
}

// K5b: out[d] = sigmoid(gate) * sum_e ctx[e]*Wp[d][e]; one wave per row
__global__ __launch_bounds__(256) void k5b_gemv(
    const float* __restrict__ Wp, const float* __restrict__ ctx,
    const float* __restrict__ gate, float* __restrict__ dout)
{
  const int tid = threadIdx.x;
  const int lane = tid & 63;
  const int w = tid >> 6;
  const int row = blockIdx.x * 4 + w;
  const float* p = Wp + row * D_MODEL;
  float s = 0.f;
#pragma unroll
  for (int i = 0; i < 8; ++i) {
    int e = lane * 4 + i * 256;
    float4 wv = *(const float4*)(p + e);
    float4 cv = *(const float4*)(ctx + e);
    s += wv.x * cv.x + wv.y * cv.y + wv.z * cv.z + wv.w * cv.w;
  }
  for (int o = 32; o > 0; o >>= 1) s += __shfl_down(s, o, 64);
  if (lane == 0) {
    float sig = 1.f / (1.f + expf(-gate[0]));
    dout[row] = s * sig;
  }
}

extern "C" void kernel_launch(void* const* d_in, const int* in_sizes, int n_in,
                              void* d_out, int out_size, void* d_ws, size_t ws_size,
                              hipStream_t stream) {
  const float* scan  = (const float*)d_in[0];
  const float* buf   = (const float*)d_in[1];
  const float* rr    = (const float*)d_in[2];
  const float* ri    = (const float*)d_in[3];
  const float* wb    = (const float*)d_in[4];
  const float* Wp    = (const float*)d_in[5];
  const float* gate  = (const float*)d_in[6];
  const float* cheby = (const float*)d_in[7];
  float* out = (float*)d_out;
  float* ws = (float*)d_ws;

  float* coeffs   = ws + OFF_COEFFS;
  float* nsq_part = ws + OFF_NSQ;
  float* norms    = ws + OFF_NORMS;
  float* part_r   = ws + OFF_PARTR;
  float* part_i   = ws + OFF_PARTI;
  float* ctx      = ws + OFF_CTX;
  bf16*  cheb2    = (bf16*)(ws + OFF_CHEB2);

  k0_prep<<<128, 256, 0, stream>>>(cheby, cheb2);
  k1_mfma<<<dim3(64, 16), 256, 0, stream>>>(scan, buf, cheb2, coeffs, nsq_part);
  k3_bind<<<dim3(3, NCHUNK), 256, 0, stream>>>(coeffs, nsq_part, rr, ri,
                                               part_r, part_i, norms, out);
  k4_ctx<<<8, 256, 0, stream>>>(norms, part_r, part_i, rr, ri, wb, out, ctx);
  k5b_gemv<<<512, 256, 0, stream>>>(Wp, ctx, gate, out);
}